// Round 4
// baseline (244.567 us; speedup 1.0000x reference)
//
#include <hip/hip_runtime.h>
#include <math.h>

#define B_   4
#define C_   256
#define CQK  32
#define N_   4096
#define TQ   64
#define TM   64
#define ITERS (N_ / TM)
#define PSS  72   // ps row stride (shorts): 144B -> bank step 4, 2-way max (free)

typedef __attribute__((ext_vector_type(8))) short short8;
typedef __attribute__((ext_vector_type(4))) short short4v;
typedef __attribute__((ext_vector_type(4))) float f32x4;
typedef __attribute__((ext_vector_type(2))) unsigned int uint2v;

__device__ __forceinline__ unsigned short f2bf(float f) {
    unsigned u = __builtin_bit_cast(unsigned, f);
    u += 0x7fffu + ((u >> 16) & 1u);
    return (unsigned short)(u >> 16);
}

// ---------- weights -> bf16 [320][256] + fp32 bias[320] ----------
__global__ __launch_bounds__(256) void cvt_w(
    const float* __restrict__ Wq, const float* __restrict__ bq,
    const float* __restrict__ Wk, const float* __restrict__ bk,
    const float* __restrict__ Wv, const float* __restrict__ bv,
    unsigned short* __restrict__ wbf, float* __restrict__ biasf)
{
    const int r = blockIdx.x;   // 0..319
    const int t = threadIdx.x;
    const float* src = (r < 32) ? (Wq + r * C_)
                     : (r < 64) ? (Wk + (r - 32) * C_)
                                : (Wv + (r - 64) * C_);
    wbf[r * C_ + t] = f2bf(src[t]);
    if (t == 0)
        biasf[r] = (r < 32) ? bq[r] : (r < 64) ? bk[r - 32] : bv[r - 64];
}

// ---------- x [b][c][n] f32 -> xT [b][n][c] bf16 ----------
// grid (N/64, B), 256 threads
__global__ __launch_bounds__(256) void xpose(
    const float* __restrict__ x, unsigned short* __restrict__ xT)
{
    const int n0 = blockIdx.x * 64;
    const int b  = blockIdx.y;
    const int nl = threadIdx.x & 63;
    const int co = (threadIdx.x >> 6) * 8;   // 0,8,16,24

    const float* xb = x + (size_t)(b * C_) * N_ + n0 + nl;
    unsigned short* ob = xT + ((size_t)(b * N_) + n0 + nl) * C_;

#pragma unroll
    for (int pass = 0; pass < 8; ++pass) {
        const int c0 = pass * 32 + co;
        short8 pk;
#pragma unroll
        for (int j = 0; j < 8; ++j)
            pk[j] = (short)f2bf(xb[(size_t)(c0 + j) * N_]);
        *(short8*)(ob + c0) = pk;
    }
}

// ---------- fused qkv projection GEMM, LDS-free ----------
// grid (N/32 = 128, B), 256 threads (4 waves); wave w owns output rows 80w..80w+79
__global__ __launch_bounds__(256) void proj_qkv(
    const unsigned short* __restrict__ xT, const unsigned short* __restrict__ wbf,
    const float* __restrict__ biasf,
    unsigned short* __restrict__ qb, unsigned short* __restrict__ kb,
    unsigned short* __restrict__ vb)
{
    const int t    = threadIdx.x;
    const int w    = t >> 6;
    const int lane = t & 63;
    const int quad = lane >> 4;
    const int c16  = lane & 15;
    const int n0   = blockIdx.x * 32;
    const int b    = blockIdx.y;

    f32x4 acc[5][2];
#pragma unroll
    for (int i = 0; i < 5; ++i)
#pragma unroll
        for (int nt = 0; nt < 2; ++nt) acc[i][nt] = (f32x4){0.f, 0.f, 0.f, 0.f};

    const unsigned short* xrow0 = xT + ((size_t)(b * N_) + n0 + c16) * C_ + quad * 8;
    const unsigned short* wrow0 = wbf + (size_t)(80 * w + c16) * C_ + quad * 8;

#pragma unroll
    for (int ks = 0; ks < 8; ++ks) {
        short8 af[5], bf[2];
#pragma unroll
        for (int i = 0; i < 5; ++i)
            af[i] = *(const short8*)(wrow0 + (size_t)(16 * i) * C_ + 32 * ks);
#pragma unroll
        for (int nt = 0; nt < 2; ++nt)
            bf[nt] = *(const short8*)(xrow0 + (size_t)(16 * nt) * C_ + 32 * ks);
#pragma unroll
        for (int i = 0; i < 5; ++i)
#pragma unroll
            for (int nt = 0; nt < 2; ++nt)
                acc[i][nt] = __builtin_amdgcn_mfma_f32_16x16x32_bf16(af[i], bf[nt], acc[i][nt], 0, 0, 0);
    }

    // epilogue
#pragma unroll
    for (int i = 0; i < 5; ++i) {
        const int OT = 5 * w + i;
        const int obase = OT * 16 + 4 * quad;
        const f32x4 bv4 = *(const f32x4*)&biasf[obase];
#pragma unroll
        for (int nt = 0; nt < 2; ++nt) {
            const int n = n0 + 16 * nt + c16;
            float vals[4];
#pragma unroll
            for (int r = 0; r < 4; ++r) vals[r] = acc[i][nt][r] + bv4[r];
            if (OT < 4) {  // q (OT 0,1) / k (OT 2,3): [b][n][32]
                unsigned short* dst = (OT < 2) ? qb : kb;
                const int o = obase - ((OT < 2) ? 0 : 32);
                short4v pk;
#pragma unroll
                for (int r = 0; r < 4; ++r) pk[r] = (short)f2bf(vals[r]);
                *(short4v*)&dst[((size_t)(b * N_) + n) * 32 + o] = pk;
            } else {       // v: [b][c][n]
#pragma unroll
                for (int r = 0; r < 4; ++r) {
                    const int c = obase + r - 64;
                    vb[((size_t)(b * C_) + c) * N_ + n] = f2bf(vals[r]);
                }
            }
        }
    }
}

// ---------- flash attention: direct-global frags, LDS only for P ----------
// grid (N/64, B), 512 threads (8 waves)
__global__ __launch_bounds__(512) void attn_kernel(
    const float* __restrict__ x,
    const unsigned short* __restrict__ qg,
    const unsigned short* __restrict__ kg,
    const unsigned short* __restrict__ vg,
    float* __restrict__ out)
{
    __shared__ __align__(16) unsigned short ps[2][TQ * PSS];  // 18.4 KB
    __shared__ float ls[4 * TQ];                              // 1 KB

    const int t    = threadIdx.x;
    const int w    = t >> 6;
    const int lane = t & 63;
    const int quad = lane >> 4;
    const int c16  = lane & 15;
    const int b    = blockIdx.y;
    const int q0   = blockIdx.x * TQ;
    // S-phase: wave handles kv-tile fs, q-tiles {2*gp, 2*gp+1}
    const int fs = w & 3, gp = w >> 2;
    // PV-phase: wave handles c 64*cg..+63, q-half qh
    const int cg = w & 3, qh = w >> 2;

    const unsigned short* kbase = kg + (size_t)(b * N_) * 32;
    const unsigned short* vbase = vg + (size_t)(b * C_) * N_;

    // hoist Q B-frags (iter-invariant)
    short8 bq0 = *(const short8*)(qg + ((size_t)(b * N_) + q0 + 16 * (2 * gp) + c16) * 32 + quad * 8);
    short8 bq1 = *(const short8*)(qg + ((size_t)(b * N_) + q0 + 16 * (2 * gp + 1) + c16) * 32 + quad * 8);
    // K A-frag for iter 0
    short8 ak = *(const short8*)(kbase + (size_t)(fs * 16 + c16) * 32 + quad * 8);

    f32x4 O[4][2];
#pragma unroll
    for (int ct = 0; ct < 4; ++ct)
#pragma unroll
        for (int qt = 0; qt < 2; ++qt) O[ct][qt] = (f32x4){0.f, 0.f, 0.f, 0.f};

    float l0 = 0.f, l1 = 0.f;
    int buf = 0;

#pragma unroll 1
    for (int it = 0; it < ITERS; ++it) {
        // ---- S^T = K.Q^T (C-layout: lane holds kv=fs*16+quad*4+r, q=16g+c16)
        const f32x4 z = {0.f, 0.f, 0.f, 0.f};
        const f32x4 s0 = __builtin_amdgcn_mfma_f32_16x16x32_bf16(ak, bq0, z, 0, 0, 0);
        const f32x4 s1 = __builtin_amdgcn_mfma_f32_16x16x32_bf16(ak, bq1, z, 0, 0, 0);
        if (it < ITERS - 1)  // prefetch next K frag
            ak = *(const short8*)(kbase + (size_t)((it + 1) * TM + fs * 16 + c16) * 32 + quad * 8);

        // ---- exp (fixed m=0), partial sums, pack P -> LDS
        float p0[4], p1[4];
        float rs0 = 0.f, rs1 = 0.f;
#pragma unroll
        for (int r = 0; r < 4; ++r) {
            p0[r] = __expf(s0[r]); rs0 += p0[r];
            p1[r] = __expf(s1[r]); rs1 += p1[r];
        }
        rs0 += __shfl_xor(rs0, 16); rs0 += __shfl_xor(rs0, 32);
        rs1 += __shfl_xor(rs1, 16); rs1 += __shfl_xor(rs1, 32);
        l0 += rs0; l1 += rs1;

        uint2v u0, u1;
        u0.x = (unsigned)f2bf(p0[0]) | ((unsigned)f2bf(p0[1]) << 16);
        u0.y = (unsigned)f2bf(p0[2]) | ((unsigned)f2bf(p0[3]) << 16);
        u1.x = (unsigned)f2bf(p1[0]) | ((unsigned)f2bf(p1[1]) << 16);
        u1.y = (unsigned)f2bf(p1[2]) | ((unsigned)f2bf(p1[3]) << 16);
        const int kvc = fs * 16 + 4 * quad;
        *(uint2v*)&ps[buf][(16 * (2 * gp) + c16) * PSS + kvc]     = u0;
        *(uint2v*)&ps[buf][(16 * (2 * gp + 1) + c16) * PSS + kvc] = u1;

        __syncthreads();  // P visible to all waves (dbuf -> single barrier/iter)

        // ---- PV: O^T[c][q] += V^T[c][kv] . P^T[kv][q]
        const int kv0 = it * TM;
        short8 bp[2][2];
#pragma unroll
        for (int qt = 0; qt < 2; ++qt)
#pragma unroll
            for (int s = 0; s < 2; ++s)
                bp[qt][s] = *(const short8*)&ps[buf][(32 * qh + 16 * qt + c16) * PSS + 32 * s + 8 * quad];

#pragma unroll
        for (int s = 0; s < 2; ++s)
#pragma unroll
            for (int ct = 0; ct < 4; ++ct) {
                const short8 av = *(const short8*)(
                    vbase + (size_t)(64 * cg + 16 * ct + c16) * N_ + kv0 + 32 * s + 8 * quad);
                O[ct][0] = __builtin_amdgcn_mfma_f32_16x16x32_bf16(av, bp[0][s], O[ct][0], 0, 0, 0);
                O[ct][1] = __builtin_amdgcn_mfma_f32_16x16x32_bf16(av, bp[1][s], O[ct][1], 0, 0, 0);
            }
        buf ^= 1;
    }

    if (quad == 0) {
        ls[fs * TQ + 16 * (2 * gp) + c16]     = l0;
        ls[fs * TQ + 16 * (2 * gp + 1) + c16] = l1;
    }
    __syncthreads();

    // ---- epilogue: out = x + O / l
#pragma unroll
    for (int qt = 0; qt < 2; ++qt) {
        const int q = 32 * qh + 16 * qt + c16;
        const float li = 1.0f / (ls[q] + ls[TQ + q] + ls[2 * TQ + q] + ls[3 * TQ + q]);
        const int n = q0 + q;
#pragma unroll
        for (int ct = 0; ct < 4; ++ct) {
#pragma unroll
            for (int r = 0; r < 4; ++r) {
                const int c = 64 * cg + 16 * ct + 4 * quad + r;
                const size_t idx = ((size_t)(b * C_) + c) * N_ + n;
                out[idx] = x[idx] + O[ct][qt][r] * li;
            }
        }
    }
}

extern "C" void kernel_launch(void* const* d_in, const int* in_sizes, int n_in,
                              void* d_out, int out_size, void* d_ws, size_t ws_size,
                              hipStream_t stream) {
    const float* x  = (const float*)d_in[0];
    const float* Wq = (const float*)d_in[1];
    const float* bq = (const float*)d_in[2];
    const float* Wk = (const float*)d_in[3];
    const float* bk = (const float*)d_in[4];
    const float* Wv = (const float*)d_in[5];
    const float* bv = (const float*)d_in[6];
    float* out = (float*)d_out;

    unsigned short* ws16 = (unsigned short*)d_ws;
    unsigned short* qb  = ws16;                              // [B][N][32]  1 MB
    unsigned short* kb  = qb + (size_t)B_ * N_ * 32;         // [B][N][32]  1 MB
    unsigned short* vb  = kb + (size_t)B_ * N_ * 32;         // [B][C][N]   8 MB
    unsigned short* xT  = vb + (size_t)B_ * C_ * N_;         // [B][N][C]   8 MB
    unsigned short* wbf = xT + (size_t)B_ * N_ * C_;         // [320][256] bf16
    float* biasf = (float*)(wbf + 320 * C_);                 // [320] fp32

    cvt_w<<<dim3(320), 256, 0, stream>>>(Wq, bq, Wk, bk, Wv, bv, wbf, biasf);
    xpose<<<dim3(N_ / 64, B_), 256, 0, stream>>>(x, xT);
    proj_qkv<<<dim3(N_ / 32, B_), 256, 0, stream>>>(xT, wbf, biasf, qb, kb, vb);
    attn_kernel<<<dim3(N_ / TQ, B_), 512, 0, stream>>>(x, qb, kb, vb, out);
}

// Round 5
// 214.631 us; speedup vs baseline: 1.1395x; 1.1395x over previous
//
#include <hip/hip_runtime.h>
#include <math.h>

#define B_   4
#define C_   256
#define CQK  32
#define N_   4096
#define TQ   64
#define TM   64
#define ITERS (N_ / TM)
#define PSS  72   // ps row stride (shorts)

typedef __attribute__((ext_vector_type(8))) short short8;
typedef __attribute__((ext_vector_type(4))) short short4v;
typedef __attribute__((ext_vector_type(4))) float f32x4;
typedef __attribute__((ext_vector_type(2))) unsigned int uint2v;

__device__ __forceinline__ unsigned short f2bf(float f) {
    unsigned u = __builtin_bit_cast(unsigned, f);
    u += 0x7fffu + ((u >> 16) & 1u);
    return (unsigned short)(u >> 16);
}

// ---------- weights -> bf16 [320][256] + fp32 bias[320] ----------
__global__ __launch_bounds__(256) void cvt_w(
    const float* __restrict__ Wq, const float* __restrict__ bq,
    const float* __restrict__ Wk, const float* __restrict__ bk,
    const float* __restrict__ Wv, const float* __restrict__ bv,
    unsigned short* __restrict__ wbf, float* __restrict__ biasf)
{
    const int r = blockIdx.x;   // 0..319
    const int t = threadIdx.x;
    const float* src = (r < 32) ? (Wq + r * C_)
                     : (r < 64) ? (Wk + (r - 32) * C_)
                                : (Wv + (r - 64) * C_);
    wbf[r * C_ + t] = f2bf(src[t]);
    if (t == 0)
        biasf[r] = (r < 32) ? bq[r] : (r < 64) ? bk[r - 32] : bv[r - 64];
}

// ---------- fused qkv projection GEMM, LDS-free, reads x directly ----------
// grid (N/32 = 128, B), 256 threads (4 waves); wave w owns output rows 80w..80w+79
__global__ __launch_bounds__(256) void proj_qkv(
    const float* __restrict__ x, const unsigned short* __restrict__ wbf,
    const float* __restrict__ biasf,
    unsigned short* __restrict__ qb, unsigned short* __restrict__ kb,
    unsigned short* __restrict__ vb)
{
    const int t    = threadIdx.x;
    const int w    = t >> 6;
    const int lane = t & 63;
    const int quad = lane >> 4;
    const int c16  = lane & 15;
    const int n0   = blockIdx.x * 32;
    const int b    = blockIdx.y;

    f32x4 acc[5][2];
#pragma unroll
    for (int i = 0; i < 5; ++i)
#pragma unroll
        for (int nt = 0; nt < 2; ++nt) acc[i][nt] = (f32x4){0.f, 0.f, 0.f, 0.f};

    const float* xb = x + (size_t)(b * C_) * N_ + n0 + c16;
    const unsigned short* wrow0 = wbf + (size_t)(80 * w + c16) * C_ + quad * 8;

#pragma unroll
    for (int ks = 0; ks < 8; ++ks) {
        short8 af[5], bf[2];
#pragma unroll
        for (int i = 0; i < 5; ++i)
            af[i] = *(const short8*)(wrow0 + (size_t)(16 * i) * C_ + 32 * ks);
#pragma unroll
        for (int nt = 0; nt < 2; ++nt) {
            const float* xc = xb + (size_t)(32 * ks + quad * 8) * N_ + 16 * nt;
#pragma unroll
            for (int j = 0; j < 8; ++j)
                bf[nt][j] = (short)f2bf(xc[(size_t)j * N_]);
        }
#pragma unroll
        for (int i = 0; i < 5; ++i)
#pragma unroll
            for (int nt = 0; nt < 2; ++nt)
                acc[i][nt] = __builtin_amdgcn_mfma_f32_16x16x32_bf16(af[i], bf[nt], acc[i][nt], 0, 0, 0);
    }

    // epilogue
#pragma unroll
    for (int i = 0; i < 5; ++i) {
        const int OT = 5 * w + i;
        const int obase = OT * 16 + 4 * quad;
        const f32x4 bv4 = *(const f32x4*)&biasf[obase];
#pragma unroll
        for (int nt = 0; nt < 2; ++nt) {
            const int n = n0 + 16 * nt + c16;
            float vals[4];
#pragma unroll
            for (int r = 0; r < 4; ++r) vals[r] = acc[i][nt][r] + bv4[r];
            if (OT < 4) {  // q (OT 0,1) / k (OT 2,3): [b][n][32]
                unsigned short* dst = (OT < 2) ? qb : kb;
                const int o = obase - ((OT < 2) ? 0 : 32);
                short4v pk;
#pragma unroll
                for (int r = 0; r < 4; ++r) pk[r] = (short)f2bf(vals[r]);
                *(short4v*)&dst[((size_t)(b * N_) + n) * 32 + o] = pk;
            } else {       // v: [b][c][n]
#pragma unroll
                for (int r = 0; r < 4; ++r) {
                    const int c = obase + r - 64;
                    vb[((size_t)(b * C_) + c) * N_ + n] = f2bf(vals[r]);
                }
            }
        }
    }
}

// ---------- flash attention: direct-global frags + register double-buffer ----------
// grid (N/64, B), 512 threads (8 waves)
__global__ __launch_bounds__(512) void attn_kernel(
    const float* __restrict__ x,
    const unsigned short* __restrict__ qg,
    const unsigned short* __restrict__ kg,
    const unsigned short* __restrict__ vg,
    float* __restrict__ out)
{
    __shared__ __align__(16) unsigned short ps[2][TQ * PSS];  // 18.4 KB
    __shared__ float ls[4 * TQ];                              // 1 KB

    const int t    = threadIdx.x;
    const int w    = t >> 6;
    const int lane = t & 63;
    const int quad = lane >> 4;
    const int c16  = lane & 15;
    const int b    = blockIdx.y;
    const int q0   = blockIdx.x * TQ;
    // S-phase: wave handles kv-tile fs, q-tiles {2*gp, 2*gp+1}
    const int fs = w & 3, gp = w >> 2;
    // PV-phase: wave handles c 64*cg..+63, q-half qh
    const int cg = w & 3, qh = w >> 2;

    const unsigned short* kbase = kg + (size_t)(b * N_) * 32;
    const unsigned short* vbase = vg + (size_t)(b * C_) * N_;

    // hoist Q B-frags (iter-invariant)
    short8 bq0 = *(const short8*)(qg + ((size_t)(b * N_) + q0 + 16 * (2 * gp) + c16) * 32 + quad * 8);
    short8 bq1 = *(const short8*)(qg + ((size_t)(b * N_) + q0 + 16 * (2 * gp + 1) + c16) * 32 + quad * 8);

    // prefetch K frag + V frags for iter 0 into registers
    short8 ak = *(const short8*)(kbase + (size_t)(fs * 16 + c16) * 32 + quad * 8);
    short8 av[2][4];
#pragma unroll
    for (int s = 0; s < 2; ++s)
#pragma unroll
        for (int ct = 0; ct < 4; ++ct)
            av[s][ct] = *(const short8*)(
                vbase + (size_t)(64 * cg + 16 * ct + c16) * N_ + 32 * s + 8 * quad);

    f32x4 O[4][2];
#pragma unroll
    for (int ct = 0; ct < 4; ++ct)
#pragma unroll
        for (int qt = 0; qt < 2; ++qt) O[ct][qt] = (f32x4){0.f, 0.f, 0.f, 0.f};

    float l0 = 0.f, l1 = 0.f;
    int buf = 0;

#pragma unroll 1
    for (int it = 0; it < ITERS; ++it) {
        // ---- S^T = K.Q^T (C-layout: lane holds kv=fs*16+quad*4+r, q=16g+c16)
        const f32x4 z = {0.f, 0.f, 0.f, 0.f};
        const f32x4 s0 = __builtin_amdgcn_mfma_f32_16x16x32_bf16(ak, bq0, z, 0, 0, 0);
        const f32x4 s1 = __builtin_amdgcn_mfma_f32_16x16x32_bf16(ak, bq1, z, 0, 0, 0);

        // ---- prefetch next iter's K + V frags (issued BEFORE the exp chain;
        //      the vmcnt(0) drain at the coming barrier completes them)
        short8 akn, avn[2][4];
        if (it < ITERS - 1) {
            const int kvn = (it + 1) * TM;
            akn = *(const short8*)(kbase + (size_t)(kvn + fs * 16 + c16) * 32 + quad * 8);
#pragma unroll
            for (int s = 0; s < 2; ++s)
#pragma unroll
                for (int ct = 0; ct < 4; ++ct)
                    avn[s][ct] = *(const short8*)(
                        vbase + (size_t)(64 * cg + 16 * ct + c16) * N_ + kvn + 32 * s + 8 * quad);
        }

        // ---- exp (fixed m=0), partial sums, pack P -> LDS
        float p0[4], p1[4];
        float rs0 = 0.f, rs1 = 0.f;
#pragma unroll
        for (int r = 0; r < 4; ++r) {
            p0[r] = __expf(s0[r]); rs0 += p0[r];
            p1[r] = __expf(s1[r]); rs1 += p1[r];
        }
        rs0 += __shfl_xor(rs0, 16); rs0 += __shfl_xor(rs0, 32);
        rs1 += __shfl_xor(rs1, 16); rs1 += __shfl_xor(rs1, 32);
        l0 += rs0; l1 += rs1;

        uint2v u0, u1;
        u0.x = (unsigned)f2bf(p0[0]) | ((unsigned)f2bf(p0[1]) << 16);
        u0.y = (unsigned)f2bf(p0[2]) | ((unsigned)f2bf(p0[3]) << 16);
        u1.x = (unsigned)f2bf(p1[0]) | ((unsigned)f2bf(p1[1]) << 16);
        u1.y = (unsigned)f2bf(p1[2]) | ((unsigned)f2bf(p1[3]) << 16);
        const int kvc = fs * 16 + 4 * quad;
        *(uint2v*)&ps[buf][(16 * (2 * gp) + c16) * PSS + kvc]     = u0;
        *(uint2v*)&ps[buf][(16 * (2 * gp + 1) + c16) * PSS + kvc] = u1;

        __syncthreads();  // P visible; V/K prefetch drained

        // ---- PV: O^T[c][q] += V^T[c][kv] . P^T[kv][q]
        short8 bp[2][2];
#pragma unroll
        for (int qt = 0; qt < 2; ++qt)
#pragma unroll
            for (int s = 0; s < 2; ++s)
                bp[qt][s] = *(const short8*)&ps[buf][(32 * qh + 16 * qt + c16) * PSS + 32 * s + 8 * quad];

#pragma unroll
        for (int s = 0; s < 2; ++s)
#pragma unroll
            for (int ct = 0; ct < 4; ++ct) {
                O[ct][0] = __builtin_amdgcn_mfma_f32_16x16x32_bf16(av[s][ct], bp[0][s], O[ct][0], 0, 0, 0);
                O[ct][1] = __builtin_amdgcn_mfma_f32_16x16x32_bf16(av[s][ct], bp[1][s], O[ct][1], 0, 0, 0);
            }

        ak = akn;
#pragma unroll
        for (int s = 0; s < 2; ++s)
#pragma unroll
            for (int ct = 0; ct < 4; ++ct) av[s][ct] = avn[s][ct];
        buf ^= 1;
    }

    if (quad == 0) {
        ls[fs * TQ + 16 * (2 * gp) + c16]     = l0;
        ls[fs * TQ + 16 * (2 * gp + 1) + c16] = l1;
    }
    __syncthreads();

    // ---- epilogue: out = x + O / l
#pragma unroll
    for (int qt = 0; qt < 2; ++qt) {
        const int q = 32 * qh + 16 * qt + c16;
        const float li = 1.0f / (ls[q] + ls[TQ + q] + ls[2 * TQ + q] + ls[3 * TQ + q]);
        const int n = q0 + q;
#pragma unroll
        for (int ct = 0; ct < 4; ++ct) {
#pragma unroll
            for (int r = 0; r < 4; ++r) {
                const int c = 64 * cg + 16 * ct + 4 * quad + r;
                const size_t idx = ((size_t)(b * C_) + c) * N_ + n;
                out[idx] = x[idx] + O[ct][qt][r] * li;
            }
        }
    }
}

extern "C" void kernel_launch(void* const* d_in, const int* in_sizes, int n_in,
                              void* d_out, int out_size, void* d_ws, size_t ws_size,
                              hipStream_t stream) {
    const float* x  = (const float*)d_in[0];
    const float* Wq = (const float*)d_in[1];
    const float* bq = (const float*)d_in[2];
    const float* Wk = (const float*)d_in[3];
    const float* bk = (const float*)d_in[4];
    const float* Wv = (const float*)d_in[5];
    const float* bv = (const float*)d_in[6];
    float* out = (float*)d_out;

    unsigned short* ws16 = (unsigned short*)d_ws;
    unsigned short* qb  = ws16;                              // [B][N][32]  1 MB
    unsigned short* kb  = qb + (size_t)B_ * N_ * 32;         // [B][N][32]  1 MB
    unsigned short* vb  = kb + (size_t)B_ * N_ * 32;         // [B][C][N]   8 MB
    unsigned short* wbf = vb + (size_t)B_ * C_ * N_;         // [320][256] bf16
    float* biasf = (float*)(wbf + 320 * C_);                 // [320] fp32

    cvt_w<<<dim3(320), 256, 0, stream>>>(Wq, bq, Wk, bk, Wv, bv, wbf, biasf);
    proj_qkv<<<dim3(N_ / 32, B_), 256, 0, stream>>>(x, wbf, biasf, qb, kb, vb);
    attn_kernel<<<dim3(N_ / TQ, B_), 512, 0, stream>>>(x, qb, kb, vb, out);
}